// Round 4
// baseline (361.253 us; speedup 1.0000x reference)
//
#include <hip/hip_runtime.h>
#include <hip/hip_bf16.h>
#include <cstdint>
#include <cstddef>

// Problem shape (fixed): x [B=16][N=2048][D=512] fp32
#define BB 16
#define NN 2048
#define DD 512

typedef _Float16 f16x8 __attribute__((ext_vector_type(8)));
typedef _Float16 f16x4 __attribute__((ext_vector_type(4)));
typedef float f32x4 __attribute__((ext_vector_type(4)));

// Async global->LDS, 16 B per lane. LDS dest = wave-uniform base + lane*16.
__device__ __forceinline__ void async_ld16(void* lds, const void* g) {
    __builtin_amdgcn_global_load_lds(
        (const __attribute__((address_space(1))) unsigned int*)(uintptr_t)g,
        (__attribute__((address_space(3))) unsigned int*)(uint32_t)(uintptr_t)lds,
        16, 0, 0);
}

// ---------------------------------------------------------------------------
// K1a: per-row inverse L2 norm (fp32 exact), cast x -> fp16, zero denom.
// ---------------------------------------------------------------------------
__global__ __launch_bounds__(256) void k_prep_rows(const float* __restrict__ x,
                                                   _Float16* __restrict__ xh,
                                                   float* __restrict__ rnorm,
                                                   float* __restrict__ denom) {
    const int row = blockIdx.x * 4 + (threadIdx.x >> 6);
    const int lane = threadIdx.x & 63;
    const float* xr = x + (size_t)row * DD;
    float4 a = ((const float4*)xr)[lane];
    float4 b = ((const float4*)xr)[lane + 64];
    float ss = a.x*a.x + a.y*a.y + a.z*a.z + a.w*a.w
             + b.x*b.x + b.y*b.y + b.z*b.z + b.w*b.w;
    #pragma unroll
    for (int o = 1; o < 64; o <<= 1) ss += __shfl_xor(ss, o);
    if (lane == 0) {
        rnorm[row] = 1.0f / sqrtf(ss);
        denom[row] = 0.0f;
    }
    _Float16* dst = xh + (size_t)row * DD;
    f16x4 v0 = {(_Float16)a.x, (_Float16)a.y, (_Float16)a.z, (_Float16)a.w};
    f16x4 v1 = {(_Float16)b.x, (_Float16)b.y, (_Float16)b.z, (_Float16)b.w};
    *(f16x4*)(dst + 4 * lane) = v0;
    *(f16x4*)(dst + 256 + 4 * lane) = v1;
}

// ---------------------------------------------------------------------------
// K1b: transpose-cast x -> vT fp16, vT[b][d][j].  64x64 tiles via LDS.
// ---------------------------------------------------------------------------
__global__ __launch_bounds__(256) void k_transpose(const float* __restrict__ x,
                                                   _Float16* __restrict__ vT) {
    __shared__ _Float16 t[64 * 72];
    const int tid = threadIdx.x;
    const int b = blockIdx.z;
    const int j0 = blockIdx.x * 64, d0 = blockIdx.y * 64;
    const float* xb = x + (size_t)b * NN * DD;
    #pragma unroll
    for (int p = 0; p < 4; ++p) {
        const int r = p * 16 + (tid >> 4);
        const int c = (tid & 15) * 4;
        float4 v = *(const float4*)(xb + (size_t)(j0 + r) * DD + d0 + c);
        t[(c + 0) * 72 + r] = (_Float16)v.x;
        t[(c + 1) * 72 + r] = (_Float16)v.y;
        t[(c + 2) * 72 + r] = (_Float16)v.z;
        t[(c + 3) * 72 + r] = (_Float16)v.w;
    }
    __syncthreads();
    #pragma unroll
    for (int p = 0; p < 2; ++p) {
        const int id = p * 256 + tid;
        const int dr = id >> 3;
        const int ch = (id & 7) * 8;
        *(uint4*)(vT + ((size_t)b * DD + d0 + dr) * NN + j0 + ch) =
            *(const uint4*)&t[dr * 72 + ch];
    }
}

// ---------------------------------------------------------------------------
// K2: W = exp( (Xh Xh^T) * rn_i * rn_j ), symmetric-triangular.
// GEMM: unchanged from R3 (async swizzled staging, 128x128, BK=64).
// Epilogue v2: two-phase. Phase 1 builds col-major WtT with cheap b64 writes
// (regs hold 4 consecutive rows of one col) -> coalesced store of W(J,I).
// Phase 2 (off-diag only): scalar-write row-major Wt -> coalesced W(I,J).
// ---------------------------------------------------------------------------
__global__ __launch_bounds__(256) void k_scores(const _Float16* __restrict__ xh,
                                                const float* __restrict__ rnorm,
                                                _Float16* __restrict__ W,
                                                float* __restrict__ denom) {
    __shared__ _Float16 smem[17408];          // As[8192] Bs[8192]; epi: 128x136
    __shared__ float rnI[128], rnJ[128];
    const int tid = threadIdx.x;
    const int lane = tid & 63, wv = tid >> 6;
    const int wr = wv >> 1, wc = wv & 1;
    const int m_ = lane & 15, quad = lane >> 4;
    const int rm = m_ & 7;
    const int b = blockIdx.z;

    int rem = blockIdx.x, ti = 0, rowlen = NN / 128;
    while (rem >= rowlen) { rem -= rowlen; ++ti; --rowlen; }
    const int tj = ti + rem;
    const int I = ti * 128, J = tj * 128;
    const bool diag = (ti == tj);

    const _Float16* Ab = xh + ((size_t)b * NN + I) * DD;
    const _Float16* Bb = xh + ((size_t)b * NN + J) * DD;
    if (tid < 128) rnI[tid] = rnorm[b * NN + I + tid];
    else           rnJ[tid - 128] = rnorm[b * NN + J + (tid - 128)];

    f32x4 acc[4][4];
    #pragma unroll
    for (int i = 0; i < 4; ++i)
        #pragma unroll
        for (int j = 0; j < 4; ++j) acc[i][j] = (f32x4){0.f, 0.f, 0.f, 0.f};

    _Float16* As = smem;
    _Float16* Bs = smem + 8192;
    const int sub = lane >> 3;
    const int swc = (lane & 7) ^ sub;
    const _Float16* agl = Ab + (size_t)(wv * 32 + sub) * DD + swc * 8;
    const _Float16* bgl = Bb + (size_t)(wv * 32 + sub) * DD + swc * 8;

    for (int kb = 0; kb < DD / 64; ++kb) {
        const int k0 = kb * 64;
        #pragma unroll
        for (int c = 0; c < 4; ++c) {
            async_ld16(&As[(wv * 32 + c * 8) * 64], agl + (size_t)c * 8 * DD + k0);
            async_ld16(&Bs[(wv * 32 + c * 8) * 64], bgl + (size_t)c * 8 * DD + k0);
        }
        __syncthreads();
        #pragma unroll
        for (int kc = 0; kc < 2; ++kc) {
            f16x8 af[4], bf[4];
            #pragma unroll
            for (int t = 0; t < 4; ++t) {
                const int Ra = wr * 64 + t * 16 + m_;
                const int Rb = wc * 64 + t * 16 + m_;
                af[t] = *(const f16x8*)&As[Ra * 64 + (((kc * 4 + quad) ^ (Ra & 7)) * 8)];
                bf[t] = *(const f16x8*)&Bs[Rb * 64 + (((kc * 4 + quad) ^ (Rb & 7)) * 8)];
            }
            #pragma unroll
            for (int i = 0; i < 4; ++i)
                #pragma unroll
                for (int j = 0; j < 4; ++j)
                    acc[i][j] = __builtin_amdgcn_mfma_f32_16x16x32_f16(af[i], bf[j], acc[i][j], 0, 0, 0);
        }
        __syncthreads();
    }

    // Epilogue: exp into packed f16x4 per (i,j); register row/col sums.
    f16x4 wq[4][4];
    float rowpart[4][4];
    float colpart[4] = {0.f, 0.f, 0.f, 0.f};
    #pragma unroll
    for (int i = 0; i < 4; ++i)
        #pragma unroll
        for (int r = 0; r < 4; ++r) rowpart[i][r] = 0.f;

    #pragma unroll
    for (int i = 0; i < 4; ++i) {
        const int rowb = wr * 64 + i * 16 + quad * 4;
        #pragma unroll
        for (int j = 0; j < 4; ++j) {
            const int col = wc * 64 + j * 16 + m_;
            const float rj = rnJ[col];
            #pragma unroll
            for (int r = 0; r < 4; ++r) {
                const float w = __expf(acc[i][j][r] * rnI[rowb + r] * rj);
                wq[i][j][r] = (_Float16)w;
                rowpart[i][r] += w;
                colpart[j] += w;
            }
        }
    }

    #pragma unroll
    for (int i = 0; i < 4; ++i) {
        #pragma unroll
        for (int r = 0; r < 4; ++r) {
            float s = rowpart[i][r];
            s += __shfl_xor(s, 1);
            s += __shfl_xor(s, 2);
            s += __shfl_xor(s, 4);
            s += __shfl_xor(s, 8);
            if (m_ == 0)
                atomicAdd(&denom[b * NN + I + wr * 64 + i * 16 + quad * 4 + r], s);
        }
    }
    if (!diag) {
        #pragma unroll
        for (int j = 0; j < 4; ++j) {
            float s = colpart[j];
            s += __shfl_xor(s, 16);
            s += __shfl_xor(s, 32);
            if (quad == 0)
                atomicAdd(&denom[b * NN + J + wc * 64 + j * 16 + m_], s);
        }
    }

    // Phase 1: WtT[col][row] (stride 136), b64 writes (4 rows contiguous).
    _Float16* WtT = smem;
    #pragma unroll
    for (int i = 0; i < 4; ++i) {
        const int rowb = wr * 64 + i * 16 + quad * 4;
        #pragma unroll
        for (int j = 0; j < 4; ++j) {
            const int col = wc * 64 + j * 16 + m_;
            *(f16x4*)&WtT[col * 136 + rowb] = wq[i][j];
        }
    }
    __syncthreads();
    // Store W(J,I): row rr of W(J,I) = WtT row rr, coalesced. Diag: (I,I)=T ok.
    {
        const int rr = tid >> 1, off = (tid & 1) * 64;
        _Float16* wg = W + ((size_t)b * NN + J + rr) * NN + I + off;
        const _Float16* wl = &WtT[rr * 136 + off];
        #pragma unroll
        for (int c = 0; c < 64; c += 8)
            *(uint4*)(wg + c) = *(const uint4*)(wl + c);
    }
    // Phase 2 (off-diag): row-major Wt, scalar writes, then coalesced W(I,J).
    if (!diag) {
        __syncthreads();
        _Float16* Wt = smem;
        #pragma unroll
        for (int i = 0; i < 4; ++i) {
            const int rowb = wr * 64 + i * 16 + quad * 4;
            #pragma unroll
            for (int j = 0; j < 4; ++j) {
                const int col = wc * 64 + j * 16 + m_;
                #pragma unroll
                for (int r = 0; r < 4; ++r)
                    Wt[(rowb + r) * 136 + col] = wq[i][j][r];
            }
        }
        __syncthreads();
        const int rr = tid >> 1, off = (tid & 1) * 64;
        _Float16* wg = W + ((size_t)b * NN + I + rr) * NN + J + off;
        const _Float16* wl = &Wt[rr * 136 + off];
        #pragma unroll
        for (int c = 0; c < 64; c += 8)
            *(uint4*)(wg + c) = *(const uint4*)(wl + c);
    }
}

// ---------------------------------------------------------------------------
// K3: O = (W @ V) * (1/denom_i), fp32 out.
// v3: 256x256 block, 4 waves of 128x128 (acc 256 VGPR), BK=32,
// double-buffered async staging (2 x 32KB LDS), ONE barrier per iter.
// LDS layout: chunk-major within 16-row groups -> lane-linear async dest,
// b128 frag reads at the 8-phase floor (no swizzle needed).
// grid (8, 2, 16) = 256 blocks = 1/CU.
// ---------------------------------------------------------------------------
__global__ __launch_bounds__(256, 1) void k_pv(const _Float16* __restrict__ W,
                                               const _Float16* __restrict__ vT,
                                               const float* __restrict__ denom,
                                               float* __restrict__ out) {
    __shared__ _Float16 smem[32768];          // 64 KB: 2 x (As 8192 + Bs 8192)
    const int tid = threadIdx.x;
    const int lane = tid & 63, wv = tid >> 6;
    const int wr = wv >> 1, wc = wv & 1;
    const int m_ = lane & 15, quad = lane >> 4;
    const int b = blockIdx.z;
    const int I = blockIdx.x * 256;
    const int D0 = blockIdx.y * 256;
    const _Float16* Ab = W + ((size_t)b * NN + I) * NN;
    const _Float16* Bb = vT + ((size_t)b * DD + D0) * NN;

    f32x4 acc[8][8];
    #pragma unroll
    for (int i = 0; i < 8; ++i)
        #pragma unroll
        for (int j = 0; j < 8; ++j) acc[i][j] = (f32x4){0.f, 0.f, 0.f, 0.f};

    // staging: wave wv stages rows [wv*64, wv*64+64) as 4 groups of 16 rows.
    // lane = ch*16 + sub: row = g*16+sub, chunk ch (8 halves).
    const int sub16 = lane & 15;
    const int ch4 = lane >> 4;
    const _Float16* agl = Ab + (size_t)(wv * 64 + sub16) * NN + ch4 * 8;
    const _Float16* bgl = Bb + (size_t)(wv * 64 + sub16) * NN + ch4 * 8;

    // prologue: stage kb=0 into buffer 0
    {
        _Float16* As = smem;
        _Float16* Bs = smem + 8192;
        #pragma unroll
        for (int c = 0; c < 4; ++c) {
            async_ld16(&As[(wv * 4 + c) * 512], agl + (size_t)c * 16 * NN);
            async_ld16(&Bs[(wv * 4 + c) * 512], bgl + (size_t)c * 16 * NN);
        }
    }
    __syncthreads();

    for (int kb = 0; kb < NN / 32; ++kb) {
        const int p = kb & 1;
        _Float16* Asp = smem + p * 16384;
        _Float16* Bsp = Asp + 8192;
        if (kb < NN / 32 - 1) {
            const int k0 = (kb + 1) * 32;
            _Float16* An = smem + (p ^ 1) * 16384;
            _Float16* Bn = An + 8192;
            #pragma unroll
            for (int c = 0; c < 4; ++c) {
                async_ld16(&An[(wv * 4 + c) * 512], agl + (size_t)c * 16 * NN + k0);
                async_ld16(&Bn[(wv * 4 + c) * 512], bgl + (size_t)c * 16 * NN + k0);
            }
        }
        f16x8 af[8], bf[8];
        #pragma unroll
        for (int t = 0; t < 8; ++t) {
            af[t] = *(const f16x8*)&Asp[wr * 4096 + t * 512 + quad * 128 + m_ * 8];
            bf[t] = *(const f16x8*)&Bsp[wc * 4096 + t * 512 + quad * 128 + m_ * 8];
        }
        #pragma unroll
        for (int i = 0; i < 8; ++i)
            #pragma unroll
            for (int j = 0; j < 8; ++j)
                acc[i][j] = __builtin_amdgcn_mfma_f32_16x16x32_f16(af[i], bf[j], acc[i][j], 0, 0, 0);
        __syncthreads();
    }

    // Epilogue: scale by 1/denom, store fp32.
    #pragma unroll
    for (int i = 0; i < 8; ++i) {
        const int rowb = wr * 128 + i * 16 + quad * 4;
        #pragma unroll
        for (int r = 0; r < 4; ++r) {
            const int row = rowb + r;
            const float sc = 1.0f / denom[b * NN + I + row];
            float* op = out + ((size_t)(b * NN + I + row)) * DD + D0 + wc * 128 + m_;
            #pragma unroll
            for (int j = 0; j < 8; ++j)
                op[j * 16] = acc[i][j][r] * sc;
        }
    }
}

// ---------------------------------------------------------------------------
extern "C" void kernel_launch(void* const* d_in, const int* in_sizes, int n_in,
                              void* d_out, int out_size, void* d_ws, size_t ws_size,
                              hipStream_t stream) {
    const float* x = (const float*)d_in[0];
    char* ws = (char*)d_ws;
    _Float16* xh    = (_Float16*)(ws);                        // 32 MiB
    _Float16* vT    = (_Float16*)(ws + (size_t)33554432);     // 32 MiB
    _Float16* W     = (_Float16*)(ws + (size_t)67108864);     // 128 MiB
    float*    rnorm = (float*)   (ws + (size_t)201326592);    // 128 KiB
    float*    denom = (float*)   (ws + (size_t)201457664);    // 128 KiB
    float*    out   = (float*)d_out;

    k_prep_rows<<<BB * NN / 4, 256, 0, stream>>>(x, xh, rnorm, denom);
    k_transpose<<<dim3(NN / 64, DD / 64, BB), 256, 0, stream>>>(x, vT);
    const int npairs = (NN / 128) * (NN / 128 + 1) / 2;   // 136
    k_scores<<<dim3(npairs, 1, BB), 256, 0, stream>>>(xh, rnorm, W, denom);
    k_pv<<<dim3(NN / 256, DD / 256, BB), 256, 0, stream>>>(W, vT, denom, out);
}

// Round 5
// 313.531 us; speedup vs baseline: 1.1522x; 1.1522x over previous
//
#include <hip/hip_runtime.h>
#include <hip/hip_bf16.h>
#include <cstdint>
#include <cstddef>

// Problem shape (fixed): x [B=16][N=2048][D=512] fp32
#define BB 16
#define NN 2048
#define DD 512

typedef _Float16 f16x8 __attribute__((ext_vector_type(8)));
typedef _Float16 f16x4 __attribute__((ext_vector_type(4)));
typedef float f32x4 __attribute__((ext_vector_type(4)));

// Async global->LDS, 16 B per lane. LDS dest = wave-uniform base + lane*16.
__device__ __forceinline__ void async_ld16(void* lds, const void* g) {
    __builtin_amdgcn_global_load_lds(
        (const __attribute__((address_space(1))) unsigned int*)(uintptr_t)g,
        (__attribute__((address_space(3))) unsigned int*)(uint32_t)(uintptr_t)lds,
        16, 0, 0);
}

// ---------------------------------------------------------------------------
// K1 (fused): read x ONCE. Per 64-row slab:
//   - per-row L2 norm (fp32 exact, wave shuffle reduce)
//   - xhn = normalized rows, fp16, row-major   (for k_scores: S = xhn xhn^T)
//   - vT  = unnormalized fp16 transpose [b][d][j] via LDS (for k_pv B-operand)
//   - denom zero-init
// grid (NN/64, BB), 256 threads. LDS 512x66 fp16 = 66 KB -> 2 blocks/CU.
// ---------------------------------------------------------------------------
__global__ __launch_bounds__(256) void k_prep(const float* __restrict__ x,
                                              _Float16* __restrict__ xhn,
                                              _Float16* __restrict__ vT,
                                              float* __restrict__ denom) {
    __shared__ _Float16 t[512 * 66];     // [d][j], pitch 66 halves
    const int tid = threadIdx.x, lane = tid & 63, w = tid >> 6;
    const int b = blockIdx.y, j0 = blockIdx.x * 64;
    if (tid < 64) denom[b * NN + j0 + tid] = 0.f;
    const float* xb = x + ((size_t)b * NN + j0) * DD;

    for (int rr = 0; rr < 16; ++rr) {
        const int jj = w * 16 + rr;                 // row within slab
        const float* xr = xb + (size_t)jj * DD;
        float4 a = ((const float4*)xr)[lane];       // d = 4*lane ..
        float4 c = ((const float4*)xr)[lane + 64];  // d = 256+4*lane ..
        float ss = a.x*a.x + a.y*a.y + a.z*a.z + a.w*a.w
                 + c.x*c.x + c.y*c.y + c.z*c.z + c.w*c.w;
        #pragma unroll
        for (int o = 1; o < 64; o <<= 1) ss += __shfl_xor(ss, o);
        const float rn = 1.0f / sqrtf(ss);
        // normalized fp16 row (coalesced 8B stores)
        _Float16* dst = xhn + ((size_t)b * NN + j0 + jj) * DD;
        f16x4 v0 = {(_Float16)(a.x*rn), (_Float16)(a.y*rn), (_Float16)(a.z*rn), (_Float16)(a.w*rn)};
        f16x4 v1 = {(_Float16)(c.x*rn), (_Float16)(c.y*rn), (_Float16)(c.z*rn), (_Float16)(c.w*rn)};
        *(f16x4*)(dst + 4 * lane) = v0;
        *(f16x4*)(dst + 256 + 4 * lane) = v1;
        // unnormalized fp16 into transposed LDS tile
        const int d0 = 4 * lane, d1 = 256 + 4 * lane;
        t[(d0 + 0) * 66 + jj] = (_Float16)a.x;
        t[(d0 + 1) * 66 + jj] = (_Float16)a.y;
        t[(d0 + 2) * 66 + jj] = (_Float16)a.z;
        t[(d0 + 3) * 66 + jj] = (_Float16)a.w;
        t[(d1 + 0) * 66 + jj] = (_Float16)c.x;
        t[(d1 + 1) * 66 + jj] = (_Float16)c.y;
        t[(d1 + 2) * 66 + jj] = (_Float16)c.z;
        t[(d1 + 3) * 66 + jj] = (_Float16)c.w;
    }
    __syncthreads();
    // store vT rows: 512 d x 8 chunks of 8 halves; 4B-aligned b32 LDS reads.
    #pragma unroll
    for (int it = 0; it < 16; ++it) {
        const int id = it * 256 + tid;
        const int d = id >> 3, ch = (id & 7) * 8;
        const uint32_t* tp = (const uint32_t*)&t[d * 66 + ch];
        uint4 v = {tp[0], tp[1], tp[2], tp[3]};
        *(uint4*)(vT + ((size_t)b * DD + d) * NN + j0 + ch) = v;
    }
}

// ---------------------------------------------------------------------------
// K2: W = exp( xhn xhn^T ), symmetric-triangular (inputs pre-normalized).
// GEMM: async swizzled staging, 128x128 block, 4 waves 64x64, BK=64.
// Epilogue: two-phase (col-major b64 -> W(J,I); row-major scalar -> W(I,J)).
// Row/col sums of quantized W -> denom via register butterflies + atomics.
// ---------------------------------------------------------------------------
__global__ __launch_bounds__(256) void k_scores(const _Float16* __restrict__ xhn,
                                                _Float16* __restrict__ W,
                                                float* __restrict__ denom) {
    __shared__ _Float16 smem[17408];          // As[8192] Bs[8192]; epi: 128x136
    const int tid = threadIdx.x;
    const int lane = tid & 63, wv = tid >> 6;
    const int wr = wv >> 1, wc = wv & 1;
    const int m_ = lane & 15, quad = lane >> 4;
    const int b = blockIdx.z;

    int rem = blockIdx.x, ti = 0, rowlen = NN / 128;
    while (rem >= rowlen) { rem -= rowlen; ++ti; --rowlen; }
    const int tj = ti + rem;
    const int I = ti * 128, J = tj * 128;
    const bool diag = (ti == tj);

    const _Float16* Ab = xhn + ((size_t)b * NN + I) * DD;
    const _Float16* Bb = xhn + ((size_t)b * NN + J) * DD;

    f32x4 acc[4][4];
    #pragma unroll
    for (int i = 0; i < 4; ++i)
        #pragma unroll
        for (int j = 0; j < 4; ++j) acc[i][j] = (f32x4){0.f, 0.f, 0.f, 0.f};

    _Float16* As = smem;
    _Float16* Bs = smem + 8192;
    const int sub = lane >> 3;
    const int swc = (lane & 7) ^ sub;
    const _Float16* agl = Ab + (size_t)(wv * 32 + sub) * DD + swc * 8;
    const _Float16* bgl = Bb + (size_t)(wv * 32 + sub) * DD + swc * 8;

    for (int kb = 0; kb < DD / 64; ++kb) {
        const int k0 = kb * 64;
        #pragma unroll
        for (int c = 0; c < 4; ++c) {
            async_ld16(&As[(wv * 32 + c * 8) * 64], agl + (size_t)c * 8 * DD + k0);
            async_ld16(&Bs[(wv * 32 + c * 8) * 64], bgl + (size_t)c * 8 * DD + k0);
        }
        __syncthreads();
        #pragma unroll
        for (int kc = 0; kc < 2; ++kc) {
            f16x8 af[4], bf[4];
            #pragma unroll
            for (int t = 0; t < 4; ++t) {
                const int Ra = wr * 64 + t * 16 + m_;
                const int Rb = wc * 64 + t * 16 + m_;
                af[t] = *(const f16x8*)&As[Ra * 64 + (((kc * 4 + quad) ^ (Ra & 7)) * 8)];
                bf[t] = *(const f16x8*)&Bs[Rb * 64 + (((kc * 4 + quad) ^ (Rb & 7)) * 8)];
            }
            #pragma unroll
            for (int i = 0; i < 4; ++i)
                #pragma unroll
                for (int j = 0; j < 4; ++j)
                    acc[i][j] = __builtin_amdgcn_mfma_f32_16x16x32_f16(af[i], bf[j], acc[i][j], 0, 0, 0);
        }
        __syncthreads();
    }

    // Epilogue: exp into packed f16x4; register row/col sums.
    f16x4 wq[4][4];
    float rowpart[4][4];
    float colpart[4] = {0.f, 0.f, 0.f, 0.f};
    #pragma unroll
    for (int i = 0; i < 4; ++i)
        #pragma unroll
        for (int r = 0; r < 4; ++r) rowpart[i][r] = 0.f;

    #pragma unroll
    for (int i = 0; i < 4; ++i) {
        #pragma unroll
        for (int j = 0; j < 4; ++j) {
            #pragma unroll
            for (int r = 0; r < 4; ++r) {
                const float w = __expf(acc[i][j][r]);
                wq[i][j][r] = (_Float16)w;
                rowpart[i][r] += w;
                colpart[j] += w;
            }
        }
    }

    #pragma unroll
    for (int i = 0; i < 4; ++i) {
        #pragma unroll
        for (int r = 0; r < 4; ++r) {
            float s = rowpart[i][r];
            s += __shfl_xor(s, 1);
            s += __shfl_xor(s, 2);
            s += __shfl_xor(s, 4);
            s += __shfl_xor(s, 8);
            if (m_ == 0)
                atomicAdd(&denom[b * NN + I + wr * 64 + i * 16 + quad * 4 + r], s);
        }
    }
    if (!diag) {
        #pragma unroll
        for (int j = 0; j < 4; ++j) {
            float s = colpart[j];
            s += __shfl_xor(s, 16);
            s += __shfl_xor(s, 32);
            if (quad == 0)
                atomicAdd(&denom[b * NN + J + wc * 64 + j * 16 + m_], s);
        }
    }

    // Phase 1: WtT[col][row] (stride 136), b64 writes -> coalesced W(J,I).
    _Float16* WtT = smem;
    #pragma unroll
    for (int i = 0; i < 4; ++i) {
        const int rowb = wr * 64 + i * 16 + quad * 4;
        #pragma unroll
        for (int j = 0; j < 4; ++j) {
            const int col = wc * 64 + j * 16 + m_;
            *(f16x4*)&WtT[col * 136 + rowb] = wq[i][j];
        }
    }
    __syncthreads();
    {
        const int rr = tid >> 1, off = (tid & 1) * 64;
        _Float16* wg = W + ((size_t)b * NN + J + rr) * NN + I + off;
        const _Float16* wl = &WtT[rr * 136 + off];
        #pragma unroll
        for (int c = 0; c < 64; c += 8)
            *(uint4*)(wg + c) = *(const uint4*)(wl + c);
    }
    // Phase 2 (off-diag): row-major Wt -> coalesced W(I,J).
    if (!diag) {
        __syncthreads();
        _Float16* Wt = smem;
        #pragma unroll
        for (int i = 0; i < 4; ++i) {
            const int rowb = wr * 64 + i * 16 + quad * 4;
            #pragma unroll
            for (int j = 0; j < 4; ++j) {
                const int col = wc * 64 + j * 16 + m_;
                #pragma unroll
                for (int r = 0; r < 4; ++r)
                    Wt[(rowb + r) * 136 + col] = wq[i][j][r];
            }
        }
        __syncthreads();
        const int rr = tid >> 1, off = (tid & 1) * 64;
        _Float16* wg = W + ((size_t)b * NN + I + rr) * NN + J + off;
        const _Float16* wl = &Wt[rr * 136 + off];
        #pragma unroll
        for (int c = 0; c < 64; c += 8)
            *(uint4*)(wg + c) = *(const uint4*)(wl + c);
    }
}

// ---------------------------------------------------------------------------
// K3: O = (W @ V) * (1/denom_i), fp32 out.  [R3 structure — known 123 us]
// Async swizzled staging, 128x128 block, 4 waves 64x64, BK=64, K=2048.
// grid (N/128, D/128, B), 256 threads.
// ---------------------------------------------------------------------------
__global__ __launch_bounds__(256) void k_pv(const _Float16* __restrict__ W,
                                            const _Float16* __restrict__ vT,
                                            const float* __restrict__ denom,
                                            float* __restrict__ out) {
    __shared__ _Float16 smem[16384];          // As[8192] Bs[8192]
    __shared__ float rdI[128];
    const int tid = threadIdx.x;
    const int lane = tid & 63, wv = tid >> 6;
    const int wr = wv >> 1, wc = wv & 1;
    const int m_ = lane & 15, quad = lane >> 4;
    const int rm = m_ & 7;
    const int b = blockIdx.z;
    const int I = blockIdx.x * 128;
    const int D0 = blockIdx.y * 128;
    const _Float16* Ab = W + ((size_t)b * NN + I) * NN;
    const _Float16* Bb = vT + ((size_t)b * DD + D0) * NN;
    if (tid < 128) rdI[tid] = 1.0f / denom[b * NN + I + tid];

    f32x4 acc[4][4];
    #pragma unroll
    for (int i = 0; i < 4; ++i)
        #pragma unroll
        for (int j = 0; j < 4; ++j) acc[i][j] = (f32x4){0.f, 0.f, 0.f, 0.f};

    _Float16* As = smem;
    _Float16* Bs = smem + 8192;

    const int sub = lane >> 3;
    const int swc = (lane & 7) ^ sub;
    const _Float16* agl = Ab + (size_t)(wv * 32 + sub) * NN + swc * 8;
    const _Float16* bgl = Bb + (size_t)(wv * 32 + sub) * NN + swc * 8;

    for (int kb = 0; kb < NN / 64; ++kb) {
        const int k0 = kb * 64;
        #pragma unroll
        for (int c = 0; c < 4; ++c) {
            async_ld16(&As[(wv * 32 + c * 8) * 64], agl + (size_t)c * 8 * NN + k0);
            async_ld16(&Bs[(wv * 32 + c * 8) * 64], bgl + (size_t)c * 8 * NN + k0);
        }
        __syncthreads();
        #pragma unroll
        for (int kc = 0; kc < 2; ++kc) {
            f16x8 af[4], bf[4];
            #pragma unroll
            for (int t = 0; t < 4; ++t) {
                const int ko = ((kc * 4 + quad) ^ rm) * 8;
                af[t] = *(const f16x8*)&As[(wr * 64 + t * 16 + m_) * 64 + ko];
                bf[t] = *(const f16x8*)&Bs[(wc * 64 + t * 16 + m_) * 64 + ko];
            }
            #pragma unroll
            for (int i = 0; i < 4; ++i)
                #pragma unroll
                for (int j = 0; j < 4; ++j)
                    acc[i][j] = __builtin_amdgcn_mfma_f32_16x16x32_f16(af[i], bf[j], acc[i][j], 0, 0, 0);
        }
        __syncthreads();
    }

    #pragma unroll
    for (int i = 0; i < 4; ++i) {
        const int rowb = wr * 64 + i * 16 + quad * 4;
        #pragma unroll
        for (int r = 0; r < 4; ++r) {
            const float sc = rdI[rowb + r];
            float* op = out + ((size_t)(b * NN + I + rowb + r)) * DD + D0;
            #pragma unroll
            for (int j = 0; j < 4; ++j)
                op[wc * 64 + j * 16 + m_] = acc[i][j][r] * sc;
        }
    }
}

// ---------------------------------------------------------------------------
extern "C" void kernel_launch(void* const* d_in, const int* in_sizes, int n_in,
                              void* d_out, int out_size, void* d_ws, size_t ws_size,
                              hipStream_t stream) {
    const float* x = (const float*)d_in[0];
    char* ws = (char*)d_ws;
    _Float16* xhn   = (_Float16*)(ws);                        // 32 MiB normalized fp16
    _Float16* vT    = (_Float16*)(ws + (size_t)33554432);     // 32 MiB fp16 x^T
    _Float16* W     = (_Float16*)(ws + (size_t)67108864);     // 128 MiB fp16 exp-scores
    float*    denom = (float*)   (ws + (size_t)201326592);    // 128 KiB
    float*    out   = (float*)d_out;

    k_prep<<<dim3(NN / 64, BB), 256, 0, stream>>>(x, xhn, vT, denom);
    const int npairs = (NN / 128) * (NN / 128 + 1) / 2;   // 136
    k_scores<<<dim3(npairs, 1, BB), 256, 0, stream>>>(xhn, W, denom);
    k_pv<<<dim3(NN / 128, DD / 128, BB), 256, 0, stream>>>(W, vT, denom, out);
}